// Round 1
// 1102.637 us; speedup vs baseline: 1.0378x; 1.0378x over previous
//
#include <hip/hip_runtime.h>
#include <hip/hip_bf16.h>
#include <cstdio>

typedef __bf16 bf16;
typedef __bf16 bf16x8 __attribute__((ext_vector_type(8)));
typedef __bf16 bf16x4 __attribute__((ext_vector_type(4)));
typedef float f32x4 __attribute__((ext_vector_type(4)));

__device__ __forceinline__ float sigmoidf_(float x) { return 1.f / (1.f + __expf(-x)); }
__device__ __forceinline__ float tanhf_(float x)    { return 1.f - 2.f / (__expf(2.f * x) + 1.f); }

// async global->LDS, 16 bytes per lane. LDS dest must be wave-uniform base +
// lane*16 (m104/m108): dest is always chunk-id * 16B with chunk tid-contiguous.
// Bank-conflict swizzle: LDS slot (row r, slot s) holds global chunk
// (r, s ^ (r&7)) of that row's 128B k-line. Readers invert: slot = want^(r&7).
__device__ __forceinline__ void gld_lds16(const bf16* g, bf16* l) {
    __builtin_amdgcn_global_load_lds(
        (const __attribute__((address_space(1))) void*)g,
        (__attribute__((address_space(3))) void*)l, 16, 0, 0);
}

// swizzled bf16x8 fragment read from a [256|rows][64] tile; kq = (khalf<<2)|q
__device__ __forceinline__ bf16x8 ldsfrag(const bf16* buf, int r, int kq) {
    int s = kq ^ (r & 7);
    return *(const bf16x8*)&buf[r * 64 + s * 8];
}

// stage 64 rows [r0, r0+64) of a row-major [rows][64] bf16 tile (row stride ld,
// k-offset kk) into linear LDS with XOR-preswizzled source. 512 threads = 1 call.
__device__ __forceinline__ void stage64(const bf16* src, int ld, int kk,
                                        bf16* dst, int r0, int tid) {
    int r  = r0 + (tid >> 3);
    int sl = tid & 7;
    int ks = (sl ^ (r & 7)) * 8;
    gld_lds16(src + (size_t)r * ld + kk + ks, dst + (r0 * 8 + tid) * 8);
}

// ---------------------------------------------------------------------------
// 256x256-tile 8-phase bf16 GEMM: C[M,N] = bf16(A[M,K] * B[N,K]^T + bias).
// 512 threads = 8 waves (2M x 4N), wave tile 128x64. BK=64, double-buffered
// 128 KiB LDS, T2 XOR swizzle, counted vmcnt (never 0 in main loop), setprio
// around MFMA clusters. Requires M%256==0, N%256==0, K%64==0, K/64 >= 2.
//
// Per K-tile: 4 phases. Phase p consumes m-frags {2p,2p+1} x (4 n-frags,
// cached per tile) x 2 k-halves = 16 MFMAs, and issues 2 staging calls of the
// NEXT tile into the other buffer. Stage order: ph0 B[0:128), ph1 B[128:256),
// ph2 A{[0:64),[128:192)}, ph3 A{[64:128),[192:256)} -- so the end-of-ph1
// wait vmcnt(4) covers this tile's late A calls and end-of-ph3 vmcnt(2)
// covers next tile's B + early-A calls, always leaving loads in flight.
// ---------------------------------------------------------------------------
__global__ __launch_bounds__(512)
void gemm256_k(const bf16* __restrict__ A, const bf16* __restrict__ B,
               bf16* __restrict__ C, const float* __restrict__ bias,
               int K, int lda, int ldb, int ldc, int nbx)
{
    __shared__ __align__(16) bf16 As[2][256 * 64];   // 2 x 32 KiB
    __shared__ __align__(16) bf16 Bs[2][256 * 64];   // 2 x 32 KiB

    const int tid  = threadIdx.x;
    const int wave = tid >> 6;
    const int lane = tid & 63;
    const int lrow = lane & 15;
    const int q    = lane >> 4;

    // XCD-affine bijective remap (gridDim.x % 8 == 0): each XCD owns a
    // contiguous chunk of the bx-fastest tile order -> A panels stay L2-hot.
    const int lb  = blockIdx.x;
    const int cpx = gridDim.x >> 3;
    const int swz = (lb & 7) * cpx + (lb >> 3);
    const int bx  = swz % nbx;
    const int by  = swz / nbx;

    const int rowbase = by * 256;
    const int colbase = bx * 256;
    const int wr = (wave >> 2) * 128;   // 2 m-waves
    const int wc = (wave & 3) * 64;     // 4 n-waves

    const bf16* Ab = A + (size_t)rowbase * lda;
    const bf16* Bb = B + (size_t)colbase * ldb;

    f32x4 acc[8][4] = {};
    const int NT = K >> 6;

#define G256_STAGE(ph, buf_, kk_)                                              \
    do {                                                                       \
        if ((ph) == 0) { stage64(Bb, ldb, (kk_), Bs[buf_],   0, tid);          \
                         stage64(Bb, ldb, (kk_), Bs[buf_],  64, tid); }        \
        if ((ph) == 1) { stage64(Bb, ldb, (kk_), Bs[buf_], 128, tid);          \
                         stage64(Bb, ldb, (kk_), Bs[buf_], 192, tid); }        \
        if ((ph) == 2) { stage64(Ab, lda, (kk_), As[buf_],   0, tid);          \
                         stage64(Ab, lda, (kk_), As[buf_], 128, tid); }        \
        if ((ph) == 3) { stage64(Ab, lda, (kk_), As[buf_],  64, tid);          \
                         stage64(Ab, lda, (kk_), As[buf_], 192, tid); }        \
    } while (0)

#define G256_PHASE(ph)                                                         \
    do {                                                                       \
        bf16x8 a00 = ldsfrag(Ac, wr + (2 * (ph) + 0) * 16 + lrow, q);          \
        bf16x8 a01 = ldsfrag(Ac, wr + (2 * (ph) + 0) * 16 + lrow, 4 | q);      \
        bf16x8 a10 = ldsfrag(Ac, wr + (2 * (ph) + 1) * 16 + lrow, q);          \
        bf16x8 a11 = ldsfrag(Ac, wr + (2 * (ph) + 1) * 16 + lrow, 4 | q);      \
        G256_STAGE(ph, nb, kkn);                                               \
        __builtin_amdgcn_s_barrier();                                          \
        __builtin_amdgcn_s_setprio(1);                                         \
        _Pragma("unroll")                                                      \
        for (int n_ = 0; n_ < 4; ++n_) {                                       \
            acc[2 * (ph) + 0][n_] = __builtin_amdgcn_mfma_f32_16x16x32_bf16(   \
                a00, bfr[n_][0], acc[2 * (ph) + 0][n_], 0, 0, 0);              \
            acc[2 * (ph) + 0][n_] = __builtin_amdgcn_mfma_f32_16x16x32_bf16(   \
                a01, bfr[n_][1], acc[2 * (ph) + 0][n_], 0, 0, 0);              \
            acc[2 * (ph) + 1][n_] = __builtin_amdgcn_mfma_f32_16x16x32_bf16(   \
                a10, bfr[n_][0], acc[2 * (ph) + 1][n_], 0, 0, 0);              \
            acc[2 * (ph) + 1][n_] = __builtin_amdgcn_mfma_f32_16x16x32_bf16(   \
                a11, bfr[n_][1], acc[2 * (ph) + 1][n_], 0, 0, 0);              \
        }                                                                      \
        __builtin_amdgcn_s_setprio(0);                                         \
    } while (0)

    // prologue: stage tile 0 into buf 0, canonical order; leave last A pair
    // in flight (mimics steady-state end-of-ph3 checkpoint).
    G256_STAGE(0, 0, 0);
    G256_STAGE(1, 0, 0);
    G256_STAGE(2, 0, 0);
    G256_STAGE(3, 0, 0);
    asm volatile("s_waitcnt vmcnt(2)\n\ts_barrier" ::: "memory");

    for (int t = 0; t < NT; ++t) {
        const int cb  = t & 1;
        const int nb  = cb ^ 1;
        const int tn  = (t + 1 < NT) ? (t + 1) : t;  // dummy restage on last
        const int kkn = tn << 6;
        const bf16* Ac = As[cb];
        const bf16* Bc = Bs[cb];

        // B-frags for this tile: read once, live in regs across 4 phases.
        bf16x8 bfr[4][2];
        #pragma unroll
        for (int n = 0; n < 4; ++n) {
            int rb = wc + n * 16 + lrow;
            bfr[n][0] = ldsfrag(Bc, rb, q);
            bfr[n][1] = ldsfrag(Bc, rb, 4 | q);
        }

        G256_PHASE(0);
        __builtin_amdgcn_s_barrier();
        G256_PHASE(1);
        // covers this tile's late-A calls; 4 newer (next tile's B) in flight
        asm volatile("s_waitcnt vmcnt(4)\n\ts_barrier" ::: "memory");
        G256_PHASE(2);
        __builtin_amdgcn_s_barrier();
        G256_PHASE(3);
        // covers next tile's B + early-A; its late-A pair stays in flight
        asm volatile("s_waitcnt vmcnt(2)\n\ts_barrier" ::: "memory");
    }
    asm volatile("s_waitcnt vmcnt(0)" ::: "memory");  // drain dummy stages

#undef G256_PHASE
#undef G256_STAGE

    #pragma unroll
    for (int m = 0; m < 8; ++m) {
        #pragma unroll
        for (int n = 0; n < 4; ++n) {
            int gr0 = rowbase + wr + m * 16 + q * 4;
            int gc  = colbase + wc + n * 16 + lrow;
            float bv = bias[gc];
            #pragma unroll
            for (int rix = 0; rix < 4; ++rix)
                C[(size_t)(gr0 + rix) * ldc + gc] = (bf16)(acc[m][n][rix] + bv);
        }
    }
}

// ---------------------------------------------------------------------------
// bf16 MFMA GEMM: C[M,N] = A[M,K] * B[N,K]^T + bias[N]. BK=64, swizzled LDS.
// Block 256 = 4 waves (2x2), wave tile (BM/2)x(BN/2). K % 64 == 0.
// (kept for the small output projection)
// ---------------------------------------------------------------------------
template<int BM, int BN, bool OUTBF16, bool NBOUND>
__global__ __launch_bounds__(256)
void gemm_lds_k(const bf16* __restrict__ A, const bf16* __restrict__ B,
                void* __restrict__ Cv, const float* __restrict__ bias,
                int K, int lda, int ldb, int ldc, int Nlim)
{
    constexpr int TM = BM / 32;
    constexpr int TN = BN / 32;

    __shared__ __align__(16) bf16 As[BM * 64];
    __shared__ __align__(16) bf16 Bs[BN * 64];

    const int tid  = threadIdx.x;
    const int wave = tid >> 6;
    const int lane = tid & 63;
    const int lrow = lane & 15;
    const int q    = lane >> 4;

    const int rowbase = blockIdx.y * BM;
    const int colbase = blockIdx.x * BN;
    const int wr = (wave >> 1) * (BM / 2);
    const int wc = (wave & 1) * (BN / 2);

    f32x4 acc[TM][TN] = {};

    for (int kk = 0; kk < K; kk += 64) {
        __syncthreads();
        #pragma unroll
        for (int i = 0; i < BM / 32; ++i) {
            int c  = tid + i * 256;
            int r  = c >> 3;
            int sl = c & 7;
            int ks = (sl ^ (r & 7)) * 8;
            gld_lds16(A + (size_t)(rowbase + r) * lda + kk + ks, &As[c * 8]);
        }
        #pragma unroll
        for (int i = 0; i < BN / 32; ++i) {
            int c  = tid + i * 256;
            int r  = c >> 3;
            int sl = c & 7;
            int ks = (sl ^ (r & 7)) * 8;
            gld_lds16(B + (size_t)(colbase + r) * ldb + kk + ks, &Bs[c * 8]);
        }
        __syncthreads();

        #pragma unroll
        for (int ks = 0; ks < 2; ++ks) {
            bf16x8 afr[TM], bfr[TN];
            #pragma unroll
            for (int m = 0; m < TM; ++m) {
                int r = wr + m * 16 + lrow;
                int s = ((ks << 2) | q) ^ (r & 7);
                afr[m] = *(const bf16x8*)&As[r * 64 + s * 8];
            }
            #pragma unroll
            for (int n = 0; n < TN; ++n) {
                int r = wc + n * 16 + lrow;
                int s = ((ks << 2) | q) ^ (r & 7);
                bfr[n] = *(const bf16x8*)&Bs[r * 64 + s * 8];
            }
            #pragma unroll
            for (int m = 0; m < TM; ++m)
                #pragma unroll
                for (int n = 0; n < TN; ++n)
                    acc[m][n] = __builtin_amdgcn_mfma_f32_16x16x32_bf16(
                                    afr[m], bfr[n], acc[m][n], 0, 0, 0);
        }
    }

    #pragma unroll
    for (int m = 0; m < TM; ++m) {
        #pragma unroll
        for (int n = 0; n < TN; ++n) {
            int gr0 = rowbase + wr + m * 16 + q * 4;
            int gc  = colbase + wc + n * 16 + lrow;
            bool cok = (!NBOUND) || (gc < Nlim);
            float bv = cok ? bias[gc] : 0.f;
            #pragma unroll
            for (int rix = 0; rix < 4; ++rix) {
                if (cok) {
                    float v = acc[m][n][rix] + bv;
                    size_t o = (size_t)(gr0 + rix) * ldc + gc;
                    if (OUTBF16) ((bf16*)Cv)[o] = (bf16)v;
                    else         ((float*)Cv)[o] = v;
                }
            }
        }
    }
}

// ---------------------------------------------------------------------------
// Fallback big GEMM (fp32 operands, cast during staging) if ws too small.
// ---------------------------------------------------------------------------
template<int BM, int BN>
__global__ __launch_bounds__(256)
void gemm_cast_k(const float* __restrict__ Av, const float* __restrict__ Bv,
                 bf16* __restrict__ Cv, const float* __restrict__ bias,
                 int K, int Klim, int lda, int ldb, int ldc)
{
    constexpr int TM = BM / 32;
    constexpr int TN = BN / 32;
    constexpr int LDK = 40;

    __shared__ __align__(16) bf16 As[BM * LDK];
    __shared__ __align__(16) bf16 Bs[BN * LDK];

    const int tid  = threadIdx.x;
    const int wave = tid >> 6;
    const int lane = tid & 63;
    const int lrow = lane & 15;
    const int q    = lane >> 4;

    const int rowbase = blockIdx.y * BM;
    const int colbase = blockIdx.x * BN;
    const int wr = (wave >> 1) * (BM / 2);
    const int wc = (wave & 1) * (BN / 2);

    f32x4 acc[TM][TN] = {};

    for (int kk = 0; kk < K; kk += 32) {
        __syncthreads();
        #pragma unroll
        for (int i = 0; i < BM / 64; ++i) {
            int c = tid + i * 256;
            int r = c >> 2, kc = (c & 3) * 8, kg = kk + kc;
            const float* src = Av + (size_t)(rowbase + r) * lda + kg;
            bf16x8 v;
            if (kg + 8 <= Klim) {
                float4 f0 = *(const float4*)(src);
                float4 f1 = *(const float4*)(src + 4);
                v[0]=(bf16)f0.x; v[1]=(bf16)f0.y; v[2]=(bf16)f0.z; v[3]=(bf16)f0.w;
                v[4]=(bf16)f1.x; v[5]=(bf16)f1.y; v[6]=(bf16)f1.z; v[7]=(bf16)f1.w;
            } else {
                #pragma unroll
                for (int e = 0; e < 8; ++e) v[e] = (kg + e < Klim) ? (bf16)src[e] : (bf16)0.f;
            }
            *(bf16x8*)&As[r * LDK + kc] = v;
        }
        #pragma unroll
        for (int i = 0; i < BN / 64; ++i) {
            int c = tid + i * 256;
            int r = c >> 2, kc = (c & 3) * 8, kg = kk + kc;
            const float* src = Bv + (size_t)(colbase + r) * ldb + kg;
            bf16x8 v;
            if (kg + 8 <= Klim) {
                float4 f0 = *(const float4*)(src);
                float4 f1 = *(const float4*)(src + 4);
                v[0]=(bf16)f0.x; v[1]=(bf16)f0.y; v[2]=(bf16)f0.z; v[3]=(bf16)f0.w;
                v[4]=(bf16)f1.x; v[5]=(bf16)f1.y; v[6]=(bf16)f1.z; v[7]=(bf16)f1.w;
            } else {
                #pragma unroll
                for (int e = 0; e < 8; ++e) v[e] = (kg + e < Klim) ? (bf16)src[e] : (bf16)0.f;
            }
            *(bf16x8*)&Bs[r * LDK + kc] = v;
        }
        __syncthreads();

        bf16x8 afr[TM], bfr[TN];
        #pragma unroll
        for (int m = 0; m < TM; ++m)
            afr[m] = *(const bf16x8*)&As[(wr + m * 16 + lrow) * LDK + q * 8];
        #pragma unroll
        for (int n = 0; n < TN; ++n)
            bfr[n] = *(const bf16x8*)&Bs[(wc + n * 16 + lrow) * LDK + q * 8];
        #pragma unroll
        for (int m = 0; m < TM; ++m)
            #pragma unroll
            for (int n = 0; n < TN; ++n)
                acc[m][n] = __builtin_amdgcn_mfma_f32_16x16x32_bf16(
                                afr[m], bfr[n], acc[m][n], 0, 0, 0);
    }

    #pragma unroll
    for (int m = 0; m < TM; ++m) {
        #pragma unroll
        for (int n = 0; n < TN; ++n) {
            int gr0 = rowbase + wr + m * 16 + q * 4;
            int gc  = colbase + wc + n * 16 + lrow;
            float bv = bias[gc];
            #pragma unroll
            for (int rix = 0; rix < 4; ++rix)
                Cv[(size_t)(gr0 + rix) * ldc + gc] = (bf16)(acc[m][n][rix] + bv);
        }
    }
}

// ---------------------------------------------------------------------------
// Fused recurrent step v4. Block = 512 threads (8 waves), grid 1D = 256 with
// XCD-affinity remap: linear block ℓ lands on XCD ℓ%8 (round-robin dispatch
// heuristic), so we decode  slot=ℓ&7, btile=(ℓ>>3)&3, hb=(ℓ>>5)*8+slot.
// => all 4 batch-tiles of one h-tile share an XCD, and each XCD owns the SAME
// 8 h-tiles every step: its W slice (8*80 rows = 1.25 MB) stays L2-resident
// across all 32 step launches instead of streaming from L3 each step.
// K=1024 split in two halves, one per 4-wave group; swizzled 128B-row LDS
// tiles; halves summed via LDS; gates in-register (no shuffles).
// ---------------------------------------------------------------------------
__global__ __launch_bounds__(512)
void step_k2(const bf16*  __restrict__ hprev,   // [256][1024]
             const bf16*  __restrict__ wsb,     // [5120][1024]
             const bf16*  __restrict__ pi_t,    // [256][6144] (b_in included)
             const float* __restrict__ b_state, // [5120]
             float*       __restrict__ cst,     // [256][1024]
             const float* __restrict__ dmask,   // [256][1024]
             bf16*        __restrict__ hnext)   // [256][1024]
{
    // 36 KB: A[2][64*64] (16KB) + B[2][80*64] (20KB); epilogue float reduction
    // (20KB) aliases the front.
    __shared__ __align__(16) unsigned char smem[36864];
    bf16* Asb = (bf16*)smem;                 // per group: [64 rows][64 k] swizzled
    bf16* Bsb = (bf16*)(smem + 16384);       // per group: [80 rows][64 k] swizzled
    float* red = (float*)smem;               // [256][5][4]

    const int tid   = threadIdx.x;
    const int wv    = tid >> 6;
    const int g2    = wv >> 2;               // K-half group
    const int wg    = wv & 3;                // m-tile within group
    const int lane  = tid & 63;
    const int lrow  = lane & 15;
    const int q     = lane >> 4;
    const int lt    = tid & 255;             // thread id within group

    // XCD-affinity decode (see header comment)
    const int lb    = blockIdx.x;
    const int hb    = (lb >> 5) * 8 + (lb & 7);
    const int hbase = hb * 16;
    const int bbase = ((lb >> 3) & 3) * 64;
    const int kbase = g2 * 512;

    bf16* Ag = Asb + g2 * 4096;
    bf16* Bg = Bsb + g2 * 5120;

    // ---- prefetch epilogue operands (group 0 only; drain during iter 0) ----
    const int b0   = bbase + wg * 16 + q * 4;
    const int hcol = hbase + lrow;
    bf16  pif[4][6];
    float crv[4], dmv[4], bsv[5];
    if (g2 == 0) {
        #pragma unroll
        for (int rix = 0; rix < 4; ++rix) {
            const bf16* pib = pi_t + (size_t)(b0 + rix) * 6144 + hcol;
            #pragma unroll
            for (int g = 0; g < 6; ++g) pif[rix][g] = pib[g * 1024];
            size_t j = (size_t)(b0 + rix) * 1024 + hcol;
            crv[rix] = cst[j];
            dmv[rix] = dmask[j];
        }
        #pragma unroll
        for (int g = 0; g < 5; ++g) bsv[g] = b_state[g * 1024 + hcol];
    }

    // ---- K-half pipeline: 8 iters of BK=64, swizzled LDS ----
    f32x4 acc[5] = {};
    for (int it = 0; it < 8; ++it) {
        const int kb = kbase + it * 64;
        __syncthreads();
        // A tile: 64 rows x 64 k -> 512 chunks
        #pragma unroll
        for (int i = 0; i < 2; ++i) {
            int c  = lt + i * 256;
            int r  = c >> 3, sl = c & 7;
            int ks = (sl ^ (r & 7)) * 8;
            gld_lds16(hprev + (size_t)(bbase + r) * 1024 + kb + ks, Ag + c * 8);
        }
        // B tile: 5 gates x 16 rows x 64 k -> 640 chunks
        #pragma unroll
        for (int i = 0; i < 3; ++i) {
            int c = lt + i * 256;
            if (c < 640) {
                int r  = c >> 3, sl = c & 7;
                int g  = r >> 4, hh = r & 15;
                int ks = (sl ^ (r & 7)) * 8;
                gld_lds16(wsb + (size_t)(g * 1024 + hbase + hh) * 1024 + kb + ks,
                          Bg + c * 8);
            }
        }
        __syncthreads();

        #pragma unroll
        for (int ks = 0; ks < 2; ++ks) {
            int ra = wg * 16 + lrow;
            int sa = ((ks << 2) | q) ^ (ra & 7);
            bf16x8 af = *(const bf16x8*)&Ag[ra * 64 + sa * 8];
            #pragma unroll
            for (int g = 0; g < 5; ++g) {
                int rb = g * 16 + lrow;
                int sb = ((ks << 2) | q) ^ (rb & 7);
                bf16x8 bv = *(const bf16x8*)&Bg[rb * 64 + sb * 8];
                acc[g] = __builtin_amdgcn_mfma_f32_16x16x32_bf16(af, bv, acc[g], 0, 0, 0);
            }
        }
    }

    // ---- combine K-halves ----
    __syncthreads();
    if (g2 == 1) {
        #pragma unroll
        for (int g = 0; g < 5; ++g)
            *(f32x4*)&red[(lt * 5 + g) * 4] = acc[g];
    }
    __syncthreads();
    if (g2 == 0) {
        #pragma unroll
        for (int g = 0; g < 5; ++g)
            acc[g] += *(const f32x4*)&red[(lt * 5 + g) * 4];

        #pragma unroll
        for (int rix = 0; rix < 4; ++rix) {
            int b = b0 + rix;
            float p0 = acc[0][rix] + bsv[0] + (float)pif[rix][0];
            float p1 = acc[1][rix] + bsv[1] + (float)pif[rix][1];
            float p2 = acc[2][rix] + bsv[2] + (float)pif[rix][2];
            float p3 = acc[3][rix] + bsv[3] + (float)pif[rix][3];
            float p4 = acc[4][rix] + bsv[4] + (float)pif[rix][4];
            float p5 = (float)pif[rix][5];

            float ig = sigmoidf_(p0);
            float fg = sigmoidf_(p1);
            float mi = tanhf_(p2);
            float og = sigmoidf_(p3);
            float hw = sigmoidf_(p4);

            size_t j = (size_t)b * 1024 + hcol;
            float mem = ig * mi + fg * crv[rix];
            cst[j] = mem;
            float out = og * tanhf_(mem);
            out = hw * out + (1.f - hw) * p5;
            out *= dmv[rix];
            hnext[j] = (bf16)out;
        }
    }
}

// ---------------------------------------------------------------------------
// casts / init
// ---------------------------------------------------------------------------
__global__ void cast_f2b4_k(const float* __restrict__ src, bf16* __restrict__ dst, int n4) {
    int i = blockIdx.x * 256 + threadIdx.x;
    if (i < n4) {
        float4 f = *(const float4*)(src + i * 4);
        bf16x4 v; v[0]=(bf16)f.x; v[1]=(bf16)f.y; v[2]=(bf16)f.z; v[3]=(bf16)f.w;
        *(bf16x4*)(dst + i * 4) = v;
    }
}

// W_out [C,H] -> bf16 [192,H], rows >= C zero-filled
__global__ void cast_wout_k(const float* __restrict__ src, bf16* __restrict__ dst, int Crows) {
    int i = blockIdx.x * 256 + threadIdx.x;    // over 192*1024
    int r = i >> 10;
    dst[i] = (r < Crows) ? (bf16)src[i] : (bf16)0.f;
}

// row-wise cast with K padding (vec4): src [rows, klim] f32 -> dst [rows, kp] bf16
__global__ void cast_pad4_k(const float* __restrict__ src, bf16* __restrict__ dst,
                            int klim, int kp) {
    int r = blockIdx.x;
    const float* s = src + (size_t)r * klim;
    bf16* d = dst + (size_t)r * kp;
    int nk4 = kp >> 2, lim4 = klim >> 2;
    for (int c = threadIdx.x; c < nk4; c += 256) {
        bf16x4 v;
        if (c < lim4) {
            float4 f = *(const float4*)(s + c * 4);
            v[0]=(bf16)f.x; v[1]=(bf16)f.y; v[2]=(bf16)f.z; v[3]=(bf16)f.w;
        } else {
            v[0]=v[1]=v[2]=v[3]=(bf16)0.f;
        }
        *(bf16x4*)(d + c * 4) = v;
    }
}

__global__ void init_state_k(const float* __restrict__ c0, const float* __restrict__ h0,
                             float* __restrict__ cst, bf16* __restrict__ hs0) {
    int i = blockIdx.x * 256 + threadIdx.x;
    cst[i] = c0[i];
    hs0[i] = (bf16)h0[i];
}

// ---------------------------------------------------------------------------
extern "C" void kernel_launch(void* const* d_in, const int* in_sizes, int n_in,
                              void* d_out, int out_size, void* d_ws, size_t ws_size,
                              hipStream_t stream)
{
    const float* x       = (const float*)d_in[0];
    const float* h0      = (const float*)d_in[1];
    const float* c0      = (const float*)d_in[2];
    const float* dmask   = (const float*)d_in[3];
    const float* W_in    = (const float*)d_in[4];
    const float* b_in    = (const float*)d_in[5];
    const float* W_state = (const float*)d_in[6];
    const float* b_state = (const float*)d_in[7];
    const float* W_out   = (const float*)d_in[8];
    const float* b_out   = (const float*)d_in[9];

    constexpr int T = 32, B = 256, DIN = 4196, H = 1024, C = 151;
    constexpr int M  = T * B;       // 8192
    constexpr int KP = 4224;        // DIN padded to multiple of 64
    constexpr int N6 = 6 * H;       // 6144
    constexpr int N5 = 5 * H;       // 5120

    size_t off = 0;
    auto carve = [&](size_t bytes) -> void* {
        void* p = (char*)d_ws + off;
        off += (bytes + 255) & ~(size_t)255;
        return p;
    };
    bf16*  pi  = (bf16*) carve((size_t)M * N6 * 2);          // 100.7 MB
    bf16*  wsb = (bf16*) carve((size_t)N5 * H * 2);          //  10.5 MB
    bf16*  wob = (bf16*) carve((size_t)192 * H * 2);         //   0.4 MB
    bf16*  hs  = (bf16*) carve((size_t)(T + 1) * B * H * 2); //  17.3 MB
    float* cst = (float*)carve((size_t)B * H * 4);           //   1.0 MB
    size_t base_need = off;

    bf16 *xb = nullptr, *wb = nullptr;
    bool precast = (ws_size >= base_need + (size_t)M * KP * 2 + (size_t)N6 * KP * 2 + 1024);
    if (precast) {
        xb = (bf16*)carve((size_t)M * KP * 2);               // 69.2 MB
        wb = (bf16*)carve((size_t)N6 * KP * 2);              // 51.9 MB
    }
    if (ws_size < base_need) {
        fprintf(stderr, "kernel_launch: ws too small (%zu < %zu)\n", ws_size, base_need);
        return;
    }

    // ---- init / weight casts ----
    hipLaunchKernelGGL(cast_f2b4_k, dim3((N5 * H / 4 + 255) / 256), dim3(256), 0, stream,
                       W_state, wsb, N5 * H / 4);
    hipLaunchKernelGGL(cast_wout_k, dim3(192 * H / 256), dim3(256), 0, stream, W_out, wob, C);
    hipLaunchKernelGGL(init_state_k, dim3(B * H / 256), dim3(256), 0, stream, c0, h0, cst, hs);

    // ---- big input-projection GEMM: pi = bf16(X @ W_in^T + b_in) ----
    if (precast) {
        hipLaunchKernelGGL(cast_pad4_k, dim3(M),  dim3(256), 0, stream, x,    xb, DIN, KP);
        hipLaunchKernelGGL(cast_pad4_k, dim3(N6), dim3(256), 0, stream, W_in, wb, DIN, KP);
        hipLaunchKernelGGL(gemm256_k,
                           dim3((M / 256) * (N6 / 256)), dim3(512), 0, stream,
                           xb, wb, pi, b_in, KP, KP, KP, N6, N6 / 256);
    } else {
        hipLaunchKernelGGL((gemm_cast_k<128, 128>),
                           dim3(N6 / 128, M / 128), dim3(256), 0, stream,
                           x, W_in, pi, b_in, KP, DIN, DIN, DIN, N6);
    }

    // ---- recurrence: 32 fused step kernels (implicit inter-kernel sync) ----
    for (int t = 0; t < T; ++t) {
        hipLaunchKernelGGL(step_k2, dim3(256), dim3(512), 0, stream,
                           hs + (size_t)t * B * H, wsb,
                           pi + (size_t)t * B * N6, b_state,
                           cst, dmask,
                           hs + (size_t)(t + 1) * B * H);
    }

    // ---- output projection: logits = hs @ W_out^T + b_out ----
    hipLaunchKernelGGL((gemm_lds_k<128, 64, false, true>),
                       dim3(192 / 64, M / 128), dim3(256), 0, stream,
                       hs + (size_t)B * H, wob, (float*)d_out, b_out,
                       H, H, H, C, C);
}

// Round 2
// 1081.299 us; speedup vs baseline: 1.0582x; 1.0197x over previous
//
#include <hip/hip_runtime.h>
#include <hip/hip_bf16.h>
#include <cstdio>

typedef __bf16 bf16;
typedef __bf16 bf16x8 __attribute__((ext_vector_type(8)));
typedef __bf16 bf16x4 __attribute__((ext_vector_type(4)));
typedef float f32x4 __attribute__((ext_vector_type(4)));

__device__ __forceinline__ float sigmoidf_(float x) { return 1.f / (1.f + __expf(-x)); }
__device__ __forceinline__ float tanhf_(float x)    { return 1.f - 2.f / (__expf(2.f * x) + 1.f); }

// async global->LDS, 16 bytes per lane. LDS dest must be wave-uniform base +
// lane*16 (m104/m108): dest is always chunk-id * 16B with chunk tid-contiguous.
// Bank-conflict swizzle: LDS slot (row r, slot s) holds global chunk
// (r, s ^ (r&7)) of that row's 128B k-line. Readers invert: slot = want^(r&7).
__device__ __forceinline__ void gld_lds16(const bf16* g, bf16* l) {
    __builtin_amdgcn_global_load_lds(
        (const __attribute__((address_space(1))) void*)g,
        (__attribute__((address_space(3))) void*)l, 16, 0, 0);
}

// swizzled bf16x8 fragment read from a [rows][64] tile; kq = (khalf<<2)|q
__device__ __forceinline__ bf16x8 ldsfrag(const bf16* buf, int r, int kq) {
    int s = kq ^ (r & 7);
    return *(const bf16x8*)&buf[r * 64 + s * 8];
}

// stage 64 rows [r0, r0+64) of a row-major [rows][64] bf16 tile (row stride ld,
// k-offset kk) into linear LDS with XOR-preswizzled source. 512 threads = 1 call.
__device__ __forceinline__ void stage64(const bf16* src, int ld, int kk,
                                        bf16* dst, int r0, int tid) {
    int r  = r0 + (tid >> 3);
    int sl = tid & 7;
    int ks = (sl ^ (r & 7)) * 8;
    gld_lds16(src + (size_t)r * ld + kk + ks, dst + (r0 * 8 + tid) * 8);
}

// ---------------------------------------------------------------------------
// 256x256-tile 8-phase bf16 GEMM: C[M,N] = bf16(A[M,K] * B[N,K]^T + bias).
// 512 threads = 8 waves (2M x 4N), wave tile 128x64. BK=64, double-buffered
// 128 KiB LDS, T2 XOR swizzle, counted vmcnt (never 0 in main loop), setprio
// around MFMA clusters. Requires M%256==0, N%256==0, K%64==0, K/64 >= 2.
// (unchanged from round 1 -- attribution isolation; L2-locality work deferred)
// ---------------------------------------------------------------------------
__global__ __launch_bounds__(512)
void gemm256_k(const bf16* __restrict__ A, const bf16* __restrict__ B,
               bf16* __restrict__ C, const float* __restrict__ bias,
               int K, int lda, int ldb, int ldc, int nbx)
{
    __shared__ __align__(16) bf16 As[2][256 * 64];   // 2 x 32 KiB
    __shared__ __align__(16) bf16 Bs[2][256 * 64];   // 2 x 32 KiB

    const int tid  = threadIdx.x;
    const int wave = tid >> 6;
    const int lane = tid & 63;
    const int lrow = lane & 15;
    const int q    = lane >> 4;

    const int lb  = blockIdx.x;
    const int cpx = gridDim.x >> 3;
    const int swz = (lb & 7) * cpx + (lb >> 3);
    const int bx  = swz % nbx;
    const int by  = swz / nbx;

    const int rowbase = by * 256;
    const int colbase = bx * 256;
    const int wr = (wave >> 2) * 128;   // 2 m-waves
    const int wc = (wave & 3) * 64;     // 4 n-waves

    const bf16* Ab = A + (size_t)rowbase * lda;
    const bf16* Bb = B + (size_t)colbase * ldb;

    f32x4 acc[8][4] = {};
    const int NT = K >> 6;

#define G256_STAGE(ph, buf_, kk_)                                              \
    do {                                                                       \
        if ((ph) == 0) { stage64(Bb, ldb, (kk_), Bs[buf_],   0, tid);          \
                         stage64(Bb, ldb, (kk_), Bs[buf_],  64, tid); }        \
        if ((ph) == 1) { stage64(Bb, ldb, (kk_), Bs[buf_], 128, tid);          \
                         stage64(Bb, ldb, (kk_), Bs[buf_], 192, tid); }        \
        if ((ph) == 2) { stage64(Ab, lda, (kk_), As[buf_],   0, tid);          \
                         stage64(Ab, lda, (kk_), As[buf_], 128, tid); }        \
        if ((ph) == 3) { stage64(Ab, lda, (kk_), As[buf_],  64, tid);          \
                         stage64(Ab, lda, (kk_), As[buf_], 192, tid); }        \
    } while (0)

#define G256_PHASE(ph)                                                         \
    do {                                                                       \
        bf16x8 a00 = ldsfrag(Ac, wr + (2 * (ph) + 0) * 16 + lrow, q);          \
        bf16x8 a01 = ldsfrag(Ac, wr + (2 * (ph) + 0) * 16 + lrow, 4 | q);      \
        bf16x8 a10 = ldsfrag(Ac, wr + (2 * (ph) + 1) * 16 + lrow, q);          \
        bf16x8 a11 = ldsfrag(Ac, wr + (2 * (ph) + 1) * 16 + lrow, 4 | q);      \
        G256_STAGE(ph, nb, kkn);                                               \
        __builtin_amdgcn_s_barrier();                                          \
        __builtin_amdgcn_s_setprio(1);                                         \
        _Pragma("unroll")                                                      \
        for (int n_ = 0; n_ < 4; ++n_) {                                       \
            acc[2 * (ph) + 0][n_] = __builtin_amdgcn_mfma_f32_16x16x32_bf16(   \
                a00, bfr[n_][0], acc[2 * (ph) + 0][n_], 0, 0, 0);              \
            acc[2 * (ph) + 0][n_] = __builtin_amdgcn_mfma_f32_16x16x32_bf16(   \
                a01, bfr[n_][1], acc[2 * (ph) + 0][n_], 0, 0, 0);              \
            acc[2 * (ph) + 1][n_] = __builtin_amdgcn_mfma_f32_16x16x32_bf16(   \
                a10, bfr[n_][0], acc[2 * (ph) + 1][n_], 0, 0, 0);              \
            acc[2 * (ph) + 1][n_] = __builtin_amdgcn_mfma_f32_16x16x32_bf16(   \
                a11, bfr[n_][1], acc[2 * (ph) + 1][n_], 0, 0, 0);              \
        }                                                                      \
        __builtin_amdgcn_s_setprio(0);                                         \
    } while (0)

    G256_STAGE(0, 0, 0);
    G256_STAGE(1, 0, 0);
    G256_STAGE(2, 0, 0);
    G256_STAGE(3, 0, 0);
    asm volatile("s_waitcnt vmcnt(2)\n\ts_barrier" ::: "memory");

    for (int t = 0; t < NT; ++t) {
        const int cb  = t & 1;
        const int nb  = cb ^ 1;
        const int tn  = (t + 1 < NT) ? (t + 1) : t;  // dummy restage on last
        const int kkn = tn << 6;
        const bf16* Ac = As[cb];
        const bf16* Bc = Bs[cb];

        bf16x8 bfr[4][2];
        #pragma unroll
        for (int n = 0; n < 4; ++n) {
            int rb = wc + n * 16 + lrow;
            bfr[n][0] = ldsfrag(Bc, rb, q);
            bfr[n][1] = ldsfrag(Bc, rb, 4 | q);
        }

        G256_PHASE(0);
        __builtin_amdgcn_s_barrier();
        G256_PHASE(1);
        asm volatile("s_waitcnt vmcnt(4)\n\ts_barrier" ::: "memory");
        G256_PHASE(2);
        __builtin_amdgcn_s_barrier();
        G256_PHASE(3);
        asm volatile("s_waitcnt vmcnt(2)\n\ts_barrier" ::: "memory");
    }
    asm volatile("s_waitcnt vmcnt(0)" ::: "memory");  // drain dummy stages

#undef G256_PHASE
#undef G256_STAGE

    #pragma unroll
    for (int m = 0; m < 8; ++m) {
        #pragma unroll
        for (int n = 0; n < 4; ++n) {
            int gr0 = rowbase + wr + m * 16 + q * 4;
            int gc  = colbase + wc + n * 16 + lrow;
            float bv = bias[gc];
            #pragma unroll
            for (int rix = 0; rix < 4; ++rix)
                C[(size_t)(gr0 + rix) * ldc + gc] = (bf16)(acc[m][n][rix] + bv);
        }
    }
}

// ---------------------------------------------------------------------------
// bf16 MFMA GEMM: C[M,N] = A[M,K] * B[N,K]^T + bias[N]. BK=64, swizzled LDS.
// Block 256 = 4 waves (2x2), wave tile (BM/2)x(BN/2). K % 64 == 0.
// (kept for the small output projection)
// ---------------------------------------------------------------------------
template<int BM, int BN, bool OUTBF16, bool NBOUND>
__global__ __launch_bounds__(256)
void gemm_lds_k(const bf16* __restrict__ A, const bf16* __restrict__ B,
                void* __restrict__ Cv, const float* __restrict__ bias,
                int K, int lda, int ldb, int ldc, int Nlim)
{
    constexpr int TM = BM / 32;
    constexpr int TN = BN / 32;

    __shared__ __align__(16) bf16 As[BM * 64];
    __shared__ __align__(16) bf16 Bs[BN * 64];

    const int tid  = threadIdx.x;
    const int wave = tid >> 6;
    const int lane = tid & 63;
    const int lrow = lane & 15;
    const int q    = lane >> 4;

    const int rowbase = blockIdx.y * BM;
    const int colbase = blockIdx.x * BN;
    const int wr = (wave >> 1) * (BM / 2);
    const int wc = (wave & 1) * (BN / 2);

    f32x4 acc[TM][TN] = {};

    for (int kk = 0; kk < K; kk += 64) {
        __syncthreads();
        #pragma unroll
        for (int i = 0; i < BM / 32; ++i) {
            int c  = tid + i * 256;
            int r  = c >> 3;
            int sl = c & 7;
            int ks = (sl ^ (r & 7)) * 8;
            gld_lds16(A + (size_t)(rowbase + r) * lda + kk + ks, &As[c * 8]);
        }
        #pragma unroll
        for (int i = 0; i < BN / 32; ++i) {
            int c  = tid + i * 256;
            int r  = c >> 3;
            int sl = c & 7;
            int ks = (sl ^ (r & 7)) * 8;
            gld_lds16(B + (size_t)(colbase + r) * ldb + kk + ks, &Bs[c * 8]);
        }
        __syncthreads();

        #pragma unroll
        for (int ks = 0; ks < 2; ++ks) {
            bf16x8 afr[TM], bfr[TN];
            #pragma unroll
            for (int m = 0; m < TM; ++m) {
                int r = wr + m * 16 + lrow;
                int s = ((ks << 2) | q) ^ (r & 7);
                afr[m] = *(const bf16x8*)&As[r * 64 + s * 8];
            }
            #pragma unroll
            for (int n = 0; n < TN; ++n) {
                int r = wc + n * 16 + lrow;
                int s = ((ks << 2) | q) ^ (r & 7);
                bfr[n] = *(const bf16x8*)&Bs[r * 64 + s * 8];
            }
            #pragma unroll
            for (int m = 0; m < TM; ++m)
                #pragma unroll
                for (int n = 0; n < TN; ++n)
                    acc[m][n] = __builtin_amdgcn_mfma_f32_16x16x32_bf16(
                                    afr[m], bfr[n], acc[m][n], 0, 0, 0);
        }
    }

    #pragma unroll
    for (int m = 0; m < TM; ++m) {
        #pragma unroll
        for (int n = 0; n < TN; ++n) {
            int gr0 = rowbase + wr + m * 16 + q * 4;
            int gc  = colbase + wc + n * 16 + lrow;
            bool cok = (!NBOUND) || (gc < Nlim);
            float bv = cok ? bias[gc] : 0.f;
            #pragma unroll
            for (int rix = 0; rix < 4; ++rix) {
                if (cok) {
                    float v = acc[m][n][rix] + bv;
                    size_t o = (size_t)(gr0 + rix) * ldc + gc;
                    if (OUTBF16) ((bf16*)Cv)[o] = (bf16)v;
                    else         ((float*)Cv)[o] = v;
                }
            }
        }
    }
}

// ---------------------------------------------------------------------------
// Fallback big GEMM (fp32 operands, cast during staging) if ws too small.
// ---------------------------------------------------------------------------
template<int BM, int BN>
__global__ __launch_bounds__(256)
void gemm_cast_k(const float* __restrict__ Av, const float* __restrict__ Bv,
                 bf16* __restrict__ Cv, const float* __restrict__ bias,
                 int K, int Klim, int lda, int ldb, int ldc)
{
    constexpr int TM = BM / 32;
    constexpr int TN = BN / 32;
    constexpr int LDK = 40;

    __shared__ __align__(16) bf16 As[BM * LDK];
    __shared__ __align__(16) bf16 Bs[BN * LDK];

    const int tid  = threadIdx.x;
    const int wave = tid >> 6;
    const int lane = tid & 63;
    const int lrow = lane & 15;
    const int q    = lane >> 4;

    const int rowbase = blockIdx.y * BM;
    const int colbase = blockIdx.x * BN;
    const int wr = (wave >> 1) * (BM / 2);
    const int wc = (wave & 1) * (BN / 2);

    f32x4 acc[TM][TN] = {};

    for (int kk = 0; kk < K; kk += 32) {
        __syncthreads();
        #pragma unroll
        for (int i = 0; i < BM / 64; ++i) {
            int c = tid + i * 256;
            int r = c >> 2, kc = (c & 3) * 8, kg = kk + kc;
            const float* src = Av + (size_t)(rowbase + r) * lda + kg;
            bf16x8 v;
            if (kg + 8 <= Klim) {
                float4 f0 = *(const float4*)(src);
                float4 f1 = *(const float4*)(src + 4);
                v[0]=(bf16)f0.x; v[1]=(bf16)f0.y; v[2]=(bf16)f0.z; v[3]=(bf16)f0.w;
                v[4]=(bf16)f1.x; v[5]=(bf16)f1.y; v[6]=(bf16)f1.z; v[7]=(bf16)f1.w;
            } else {
                #pragma unroll
                for (int e = 0; e < 8; ++e) v[e] = (kg + e < Klim) ? (bf16)src[e] : (bf16)0.f;
            }
            *(bf16x8*)&As[r * LDK + kc] = v;
        }
        #pragma unroll
        for (int i = 0; i < BN / 64; ++i) {
            int c = tid + i * 256;
            int r = c >> 2, kc = (c & 3) * 8, kg = kk + kc;
            const float* src = Bv + (size_t)(colbase + r) * ldb + kg;
            bf16x8 v;
            if (kg + 8 <= Klim) {
                float4 f0 = *(const float4*)(src);
                float4 f1 = *(const float4*)(src + 4);
                v[0]=(bf16)f0.x; v[1]=(bf16)f0.y; v[2]=(bf16)f0.z; v[3]=(bf16)f0.w;
                v[4]=(bf16)f1.x; v[5]=(bf16)f1.y; v[6]=(bf16)f1.z; v[7]=(bf16)f1.w;
            } else {
                #pragma unroll
                for (int e = 0; e < 8; ++e) v[e] = (kg + e < Klim) ? (bf16)src[e] : (bf16)0.f;
            }
            *(bf16x8*)&Bs[r * LDK + kc] = v;
        }
        __syncthreads();

        bf16x8 afr[TM], bfr[TN];
        #pragma unroll
        for (int m = 0; m < TM; ++m)
            afr[m] = *(const bf16x8*)&As[(wr + m * 16 + lrow) * LDK + q * 8];
        #pragma unroll
        for (int n = 0; n < TN; ++n)
            bfr[n] = *(const bf16x8*)&Bs[(wc + n * 16 + lrow) * LDK + q * 8];
        #pragma unroll
        for (int m = 0; m < TM; ++m)
            #pragma unroll
            for (int n = 0; n < TN; ++n)
                acc[m][n] = __builtin_amdgcn_mfma_f32_16x16x32_bf16(
                                afr[m], bfr[n], acc[m][n], 0, 0, 0);
    }

    #pragma unroll
    for (int m = 0; m < TM; ++m) {
        #pragma unroll
        for (int n = 0; n < TN; ++n) {
            int gr0 = rowbase + wr + m * 16 + q * 4;
            int gc  = colbase + wc + n * 16 + lrow;
            float bv = bias[gc];
            #pragma unroll
            for (int rix = 0; rix < 4; ++rix)
                Cv[(size_t)(gr0 + rix) * ldc + gc] = (bf16)(acc[m][n][rix] + bv);
        }
    }
}

// ---------------------------------------------------------------------------
// Fused recurrent step v5. Block = 256 threads (4 waves), grid = 512 with
// XCD-affinity remap: slot=lb&7 -> XCD; hb=(lb>>6)*8+slot (same 8 h-tiles per
// XCD as v4, W slice 1.25 MB stays L2-resident across steps); btile=(lb>>3)&7
// gives 8 batch-tiles of 32 rows. 56 KB LDS -> 2 blocks/CU: co-resident
// blocks cover each other's barrier/load stalls (v4 had 1 block/CU and a full
// vmcnt(0) drain per iteration with nothing to overlap).
// Pipeline: double-buffered LDS, stage(it+1) issued BEFORE compute(it), one
// counted vmcnt(0)+s_barrier per iteration (T3-minimum schedule).
// Waves: g2=wave>>1 K-half (512 k each), wg=wave&1 m-tile (16 rows).
// ---------------------------------------------------------------------------
__global__ __launch_bounds__(256)
void step_k3(const bf16*  __restrict__ hprev,   // [256][1024]
             const bf16*  __restrict__ wsb,     // [5120][1024]
             const bf16*  __restrict__ pi_t,    // [256][6144] (b_in included)
             const float* __restrict__ b_state, // [5120]
             float*       __restrict__ cst,     // [256][1024]
             const float* __restrict__ dmask,   // [256][1024]
             bf16*        __restrict__ hnext)   // [256][1024]
{
    // per K-group: A dbuf 2x[32][64] (8 KB) + B dbuf 2x[80][64] (20 KB) = 28 KB
    // x2 groups = 56 KB. Epilogue reduction (10 KB) aliases the front.
    __shared__ __align__(16) unsigned char smem[57344];
    float* red = (float*)smem;               // [128][5][4] (after final barrier)

    const int tid   = threadIdx.x;
    const int wv    = tid >> 6;
    const int g2    = wv >> 1;               // K-half group
    const int wg    = wv & 1;                // m-tile within group
    const int lane  = tid & 63;
    const int lrow  = lane & 15;
    const int q     = lane >> 4;
    const int lt    = tid & 127;             // thread id within group

    // XCD-affinity decode (see header comment)
    const int lb    = blockIdx.x;
    const int hb    = (lb >> 6) * 8 + (lb & 7);
    const int hbase = hb * 16;
    const int bbase = ((lb >> 3) & 7) * 32;
    const int kbase = g2 * 512;

    bf16* Agrp = (bf16*)(smem + g2 * 28672);          // A bufs: +0, +2048 elems
    bf16* Bgrp = (bf16*)(smem + g2 * 28672 + 8192);   // B bufs: +0, +5120 elems

    // ---- prefetch epilogue operands (group 0 only; drains under the loop) ----
    const int b0   = bbase + wg * 16 + q * 4;
    const int hcol = hbase + lrow;
    bf16  pif[4][6];
    float crv[4], dmv[4], bsv[5];
    if (g2 == 0) {
        #pragma unroll
        for (int rix = 0; rix < 4; ++rix) {
            const bf16* pib = pi_t + (size_t)(b0 + rix) * 6144 + hcol;
            #pragma unroll
            for (int g = 0; g < 6; ++g) pif[rix][g] = pib[g * 1024];
            size_t j = (size_t)(b0 + rix) * 1024 + hcol;
            crv[rix] = cst[j];
            dmv[rix] = dmask[j];
        }
        #pragma unroll
        for (int g = 0; g < 5; ++g) bsv[g] = b_state[g * 1024 + hcol];
    }

    // staging of one BK=64 tile into buffer bf: A 256 chunks + B 640 chunks,
    // 7 gld_lds16 per thread (128 threads per group).
#define S3_STAGE(it_, bf_)                                                     \
    do {                                                                       \
        const int kb_ = kbase + (it_) * 64;                                    \
        bf16* Ad_ = Agrp + (bf_) * 2048;                                       \
        bf16* Bd_ = Bgrp + (bf_) * 5120;                                       \
        _Pragma("unroll")                                                      \
        for (int i_ = 0; i_ < 2; ++i_) {                                       \
            int c_  = lt + i_ * 128;                                           \
            int r_  = c_ >> 3, sl_ = c_ & 7;                                   \
            int ks_ = (sl_ ^ (r_ & 7)) * 8;                                    \
            gld_lds16(hprev + (size_t)(bbase + r_) * 1024 + kb_ + ks_,         \
                      Ad_ + c_ * 8);                                           \
        }                                                                      \
        _Pragma("unroll")                                                      \
        for (int i_ = 0; i_ < 5; ++i_) {                                       \
            int c_  = lt + i_ * 128;                                           \
            int r_  = c_ >> 3, sl_ = c_ & 7;                                   \
            int g_  = r_ >> 4, hh_ = r_ & 15;                                  \
            int ks_ = (sl_ ^ (r_ & 7)) * 8;                                    \
            gld_lds16(wsb + (size_t)(g_ * 1024 + hbase + hh_) * 1024 + kb_ + ks_, \
                      Bd_ + c_ * 8);                                           \
        }                                                                      \
    } while (0)

    // ---- K-half pipeline: 8 iters of BK=64, dbuf, stage-ahead ----
    f32x4 acc[5] = {};
    S3_STAGE(0, 0);
    asm volatile("s_waitcnt vmcnt(0)\n\ts_barrier" ::: "memory");

    for (int it = 0; it < 8; ++it) {
        const int cur = it & 1;
        if (it < 7) S3_STAGE(it + 1, cur ^ 1);

        const bf16* Ac = Agrp + cur * 2048;
        const bf16* Bc = Bgrp + cur * 5120;
        const int ra = wg * 16 + lrow;
        #pragma unroll
        for (int ks = 0; ks < 2; ++ks) {
            bf16x8 af = ldsfrag(Ac, ra, (ks << 2) | q);
            #pragma unroll
            for (int g = 0; g < 5; ++g) {
                bf16x8 bv = ldsfrag(Bc, g * 16 + lrow, (ks << 2) | q);
                acc[g] = __builtin_amdgcn_mfma_f32_16x16x32_bf16(af, bv, acc[g], 0, 0, 0);
            }
        }
        asm volatile("s_waitcnt vmcnt(0)\n\ts_barrier" ::: "memory");
    }
#undef S3_STAGE

    // ---- combine K-halves ----
    __syncthreads();
    if (g2 == 1) {
        #pragma unroll
        for (int g = 0; g < 5; ++g)
            *(f32x4*)&red[(lt * 5 + g) * 4] = acc[g];
    }
    __syncthreads();
    if (g2 == 0) {
        #pragma unroll
        for (int g = 0; g < 5; ++g)
            acc[g] += *(const f32x4*)&red[(lt * 5 + g) * 4];

        #pragma unroll
        for (int rix = 0; rix < 4; ++rix) {
            int b = b0 + rix;
            float p0 = acc[0][rix] + bsv[0] + (float)pif[rix][0];
            float p1 = acc[1][rix] + bsv[1] + (float)pif[rix][1];
            float p2 = acc[2][rix] + bsv[2] + (float)pif[rix][2];
            float p3 = acc[3][rix] + bsv[3] + (float)pif[rix][3];
            float p4 = acc[4][rix] + bsv[4] + (float)pif[rix][4];
            float p5 = (float)pif[rix][5];

            float ig = sigmoidf_(p0);
            float fg = sigmoidf_(p1);
            float mi = tanhf_(p2);
            float og = sigmoidf_(p3);
            float hw = sigmoidf_(p4);

            size_t j = (size_t)b * 1024 + hcol;
            float mem = ig * mi + fg * crv[rix];
            cst[j] = mem;
            float out = og * tanhf_(mem);
            out = hw * out + (1.f - hw) * p5;
            out *= dmv[rix];
            hnext[j] = (bf16)out;
        }
    }
}

// ---------------------------------------------------------------------------
// casts / init
// ---------------------------------------------------------------------------
__global__ void cast_f2b4_k(const float* __restrict__ src, bf16* __restrict__ dst, int n4) {
    int i = blockIdx.x * 256 + threadIdx.x;
    if (i < n4) {
        float4 f = *(const float4*)(src + i * 4);
        bf16x4 v; v[0]=(bf16)f.x; v[1]=(bf16)f.y; v[2]=(bf16)f.z; v[3]=(bf16)f.w;
        *(bf16x4*)(dst + i * 4) = v;
    }
}

// W_out [C,H] -> bf16 [192,H], rows >= C zero-filled
__global__ void cast_wout_k(const float* __restrict__ src, bf16* __restrict__ dst, int Crows) {
    int i = blockIdx.x * 256 + threadIdx.x;    // over 192*1024
    int r = i >> 10;
    dst[i] = (r < Crows) ? (bf16)src[i] : (bf16)0.f;
}

// row-wise cast with K padding (vec4): src [rows, klim] f32 -> dst [rows, kp] bf16
__global__ void cast_pad4_k(const float* __restrict__ src, bf16* __restrict__ dst,
                            int klim, int kp) {
    int r = blockIdx.x;
    const float* s = src + (size_t)r * klim;
    bf16* d = dst + (size_t)r * kp;
    int nk4 = kp >> 2, lim4 = klim >> 2;
    for (int c = threadIdx.x; c < nk4; c += 256) {
        bf16x4 v;
        if (c < lim4) {
            float4 f = *(const float4*)(s + c * 4);
            v[0]=(bf16)f.x; v[1]=(bf16)f.y; v[2]=(bf16)f.z; v[3]=(bf16)f.w;
        } else {
            v[0]=v[1]=v[2]=v[3]=(bf16)0.f;
        }
        *(bf16x4*)(d + c * 4) = v;
    }
}

__global__ void init_state_k(const float* __restrict__ c0, const float* __restrict__ h0,
                             float* __restrict__ cst, bf16* __restrict__ hs0) {
    int i = blockIdx.x * 256 + threadIdx.x;
    cst[i] = c0[i];
    hs0[i] = (bf16)h0[i];
}

// ---------------------------------------------------------------------------
extern "C" void kernel_launch(void* const* d_in, const int* in_sizes, int n_in,
                              void* d_out, int out_size, void* d_ws, size_t ws_size,
                              hipStream_t stream)
{
    const float* x       = (const float*)d_in[0];
    const float* h0      = (const float*)d_in[1];
    const float* c0      = (const float*)d_in[2];
    const float* dmask   = (const float*)d_in[3];
    const float* W_in    = (const float*)d_in[4];
    const float* b_in    = (const float*)d_in[5];
    const float* W_state = (const float*)d_in[6];
    const float* b_state = (const float*)d_in[7];
    const float* W_out   = (const float*)d_in[8];
    const float* b_out   = (const float*)d_in[9];

    constexpr int T = 32, B = 256, DIN = 4196, H = 1024, C = 151;
    constexpr int M  = T * B;       // 8192
    constexpr int KP = 4224;        // DIN padded to multiple of 64
    constexpr int N6 = 6 * H;       // 6144
    constexpr int N5 = 5 * H;       // 5120

    size_t off = 0;
    auto carve = [&](size_t bytes) -> void* {
        void* p = (char*)d_ws + off;
        off += (bytes + 255) & ~(size_t)255;
        return p;
    };
    bf16*  pi  = (bf16*) carve((size_t)M * N6 * 2);          // 100.7 MB
    bf16*  wsb = (bf16*) carve((size_t)N5 * H * 2);          //  10.5 MB
    bf16*  wob = (bf16*) carve((size_t)192 * H * 2);         //   0.4 MB
    bf16*  hs  = (bf16*) carve((size_t)(T + 1) * B * H * 2); //  17.3 MB
    float* cst = (float*)carve((size_t)B * H * 4);           //   1.0 MB
    size_t base_need = off;

    bf16 *xb = nullptr, *wb = nullptr;
    bool precast = (ws_size >= base_need + (size_t)M * KP * 2 + (size_t)N6 * KP * 2 + 1024);
    if (precast) {
        xb = (bf16*)carve((size_t)M * KP * 2);               // 69.2 MB
        wb = (bf16*)carve((size_t)N6 * KP * 2);              // 51.9 MB
    }
    if (ws_size < base_need) {
        fprintf(stderr, "kernel_launch: ws too small (%zu < %zu)\n", ws_size, base_need);
        return;
    }

    // ---- init / weight casts ----
    hipLaunchKernelGGL(cast_f2b4_k, dim3((N5 * H / 4 + 255) / 256), dim3(256), 0, stream,
                       W_state, wsb, N5 * H / 4);
    hipLaunchKernelGGL(cast_wout_k, dim3(192 * H / 256), dim3(256), 0, stream, W_out, wob, C);
    hipLaunchKernelGGL(init_state_k, dim3(B * H / 256), dim3(256), 0, stream, c0, h0, cst, hs);

    // ---- big input-projection GEMM: pi = bf16(X @ W_in^T + b_in) ----
    if (precast) {
        hipLaunchKernelGGL(cast_pad4_k, dim3(M),  dim3(256), 0, stream, x,    xb, DIN, KP);
        hipLaunchKernelGGL(cast_pad4_k, dim3(N6), dim3(256), 0, stream, W_in, wb, DIN, KP);
        hipLaunchKernelGGL(gemm256_k,
                           dim3((M / 256) * (N6 / 256)), dim3(512), 0, stream,
                           xb, wb, pi, b_in, KP, KP, KP, N6, N6 / 256);
    } else {
        hipLaunchKernelGGL((gemm_cast_k<128, 128>),
                           dim3(N6 / 128, M / 128), dim3(256), 0, stream,
                           x, W_in, pi, b_in, KP, DIN, DIN, DIN, N6);
    }

    // ---- recurrence: 32 fused step kernels (implicit inter-kernel sync) ----
    for (int t = 0; t < T; ++t) {
        hipLaunchKernelGGL(step_k3, dim3(512), dim3(256), 0, stream,
                           hs + (size_t)t * B * H, wsb,
                           pi + (size_t)t * B * N6, b_state,
                           cst, dmask,
                           hs + (size_t)(t + 1) * B * H);
    }

    // ---- output projection: logits = hs @ W_out^T + b_out ----
    hipLaunchKernelGGL((gemm_lds_k<128, 64, false, true>),
                       dim3(192 / 64, M / 128), dim3(256), 0, stream,
                       hs + (size_t)B * H, wob, (float*)d_out, b_out,
                       H, H, H, C, C);
}